// Round 18
// baseline (442.825 us; speedup 1.0000x reference)
//
#include <hip/hip_runtime.h>

// PWC-Net cost volume, fp32. B=4, C=128, H=256, W=448, 81 shifts.
// out[b, di*9+dj, h, w] = (1/128) * sum_c feat1[b,c,h,w] * feat2[b,c,h+di-4,w+dj-4]
//
// Block = (b,h), 1024 thr / 16 waves. Thread owns ONE 4-px quad:
// it = tid -> di = it/112, G = it%112 (1008 active). acc[9][4] = 36 regs.
// VGPR budget <= 64 (8 waves/SIMD -> 2 resident 1024-thr blocks). R16=48;
// +8 f1 ping-pong + misc ~= 58.
//
// Per channel one LDS buffer: 9 rows x 114 atoms(16B) = feat2 h-4..h+4 (OOB
// rows staged as zeros from zws). Atom a covers cols 4a-4..4a-1; atoms 0/113
// = halo, zeroed once, never staged. Thread reads f2 atoms G,G+1,G+2 (3x
// ds_read_b128, lane-stride-16B = free 2-way). f1 (own quad, no sharing) is
// a REGISTER ping-pong load from global (L1 absorbs the 9x di redundancy) —
// moving it out of LDS cuts DS/body 1008->792 cy (the R16-measured wall).
//
// Ring-3, drain-old counted vmcnt. Body t: wait vmcnt(nIss) (drains f1(t)
// [issued 1 body ago] + stage(t) [2 bodies ago]; leaves stage(t+1));
// barrier; f1next(t+1); STAGE(t+2); compute(t); f1cur=f1next. f1 issued
// BEFORE stage (FIFO) so vmcnt(nIss) drains it next body; sched_barrier
// pins the order. Stage = 18 issues: wave wid takes j=wid (+16+wid if
// wid<2); nIss = wid<2 ? 2 : 1.

typedef __attribute__((ext_vector_type(4))) float f32x4;

#define GLAS(p) ((const __attribute__((address_space(1))) unsigned int*)(p))
#define LDAS(p) ((__attribute__((address_space(3))) unsigned int*)(p))

__global__ __launch_bounds__(1024, 4) void cv_kernel(
    const float* __restrict__ feat1,
    const float* __restrict__ feat2,
    const float* __restrict__ zws,
    float* __restrict__ out)
{
    constexpr int C = 128, H = 256, W = 448;
    constexpr size_t HW = (size_t)H * W;
    constexpr int ROWB = 114 * 16;     // 1824 B
    constexpr int BUFB = 9 * ROWB;     // 16416 B
    __shared__ __align__(16) char f2s[3 * BUFB];   // 49248 B

    const int tid  = threadIdx.x;
    const int wid  = tid >> 6;
    const int lane = tid & 63;

    // XCD-contiguous (b,h) mapping (1024 = 8*128, bijective)
    const int lin = (blockIdx.x & 7) * 128 + (blockIdx.x >> 3);
    const int b = lin >> 8, h = lin & 255;

    const int it = (tid < 1008) ? tid : 1007;
    const int di = it / 112;
    const int G  = it - di * 112;      // 0..111

    // Zero LDS once (halo atoms 0/113 persist; staged atoms overwritten).
    for (int i = tid; i < (int)sizeof(f2s) / 16; i += 1024)
        *(f32x4*)(f2s + i * 16) = (f32x4){0.f, 0.f, 0.f, 0.f};

    // Staging: 18 issues. Issue j: row r=j>>1 (0..8), half hf=j&1.
    // Lanes 0..55: 16B from feat2 row (h+r-4) col hf*224+lane*4
    //   -> dest r*ROWB + 16 + hf*896 (atoms 1..112, linear). OOB row -> zws.
    const int nIss = (wid < 2) ? 2 : 1;
    const float* sp[2]; unsigned sstep[2]; int sdst[2];
#pragma unroll
    for (int k = 0; k < 2; ++k) {
        if (k < nIss) {
            const int j  = wid + 16 * k;
            const int r  = j >> 1, hf = j & 1;
            const int colf = hf * 224 + ((lane < 56) ? lane * 4 : 220);
            const int hr = h + r - 4;
            const bool ok = (hr >= 0) && (hr < H);
            sp[k] = ok ? (feat2 + ((size_t)b * C * H + (size_t)hr) * W + colf) : zws;
            sstep[k] = ok ? (unsigned)HW : 0u;
            sdst[k] = r * ROWB + 16 + hf * 896;
        }
    }

    // f2 read offset: atoms G (L), G+1 (C), G+2 (R) of row di.
    const int r2o = di * ROWB + G * 16;
    // f1: own quad, register ping-pong from global.
    unsigned f1o = (unsigned)(((b * C * H) + h) * W + G * 4);

    float acc[9][4];
#pragma unroll
    for (int j = 0; j < 9; ++j)
#pragma unroll
        for (int p = 0; p < 4; ++p) acc[j][p] = 0.0f;

    __syncthreads();   // LDS zeros visible before first stage lands

#define STAGE(BUFOFS) do { \
    _Pragma("unroll") \
    for (int k = 0; k < 2; ++k) { \
        if (k < nIss) { \
            if (lane < 56) \
                __builtin_amdgcn_global_load_lds(GLAS(sp[k]), \
                    LDAS(f2s + (BUFOFS) + sdst[k]), 16, 0, 0); \
            sp[k] += sstep[k]; \
        } \
    } } while (0)

#define COMP(BUFOFS) do { \
    const char* lb = f2s + (BUFOFS); \
    const f32x4 L  = *(const f32x4*)(lb + r2o); \
    const f32x4 Cq = *(const f32x4*)(lb + r2o + 16); \
    const f32x4 R  = *(const f32x4*)(lb + r2o + 32); \
    const float w[12] = {L.x, L.y, L.z, L.w, Cq.x, Cq.y, Cq.z, Cq.w, \
                         R.x, R.y, R.z, R.w}; \
    const float a[4] = {f1cur.x, f1cur.y, f1cur.z, f1cur.w}; \
    _Pragma("unroll") \
    for (int dj = 0; dj < 9; ++dj) { \
        _Pragma("unroll") \
        for (int p = 0; p < 4; ++p) \
            acc[dj][p] = fmaf(a[p], w[dj + p], acc[dj][p]); \
    } } while (0)

// MODE 0: wait n, reg, stage | 1: wait n, reg only | 2: wait 0, nothing
#define BODY(BUF, NBUF, MODE) do { \
    if ((MODE) <= 1) { \
        if (wid < 2) asm volatile("s_waitcnt vmcnt(2)" ::: "memory"); \
        else         asm volatile("s_waitcnt vmcnt(1)" ::: "memory"); \
    } else { \
        asm volatile("s_waitcnt vmcnt(0)" ::: "memory"); \
    } \
    __builtin_amdgcn_s_barrier(); \
    __builtin_amdgcn_sched_barrier(0); \
    f32x4 f1next; \
    if ((MODE) <= 1) { \
        f1next = *(const f32x4*)(feat1 + f1o); f1o += (unsigned)HW; \
        __builtin_amdgcn_sched_barrier(0); \
    } \
    if ((MODE) == 0) STAGE((NBUF) * BUFB); \
    __builtin_amdgcn_sched_barrier(0); \
    COMP((BUF) * BUFB); \
    if ((MODE) <= 1) f1cur = f1next; \
  } while (0)

    // Prologue: stage ch0 -> buf0; f1(0) -> f1cur.
    STAGE(0 * BUFB);
    f32x4 f1cur = *(const f32x4*)(feat1 + f1o); f1o += (unsigned)HW;

    // Body 0 (special): drain prologue; stage ch1->buf1, ch2->buf2.
    {
        asm volatile("s_waitcnt vmcnt(0)" ::: "memory");
        __builtin_amdgcn_s_barrier();
        __builtin_amdgcn_sched_barrier(0);
        f32x4 f1next = *(const f32x4*)(feat1 + f1o); f1o += (unsigned)HW;
        __builtin_amdgcn_sched_barrier(0);
        STAGE(1 * BUFB);
        STAGE(2 * BUFB);
        __builtin_amdgcn_sched_barrier(0);
        COMP(0 * BUFB);
        f1cur = f1next;
    }

    // Bodies 1..123 (41 x 3), then 124,125 (normal), 126 (reg only), 127.
#pragma unroll 1
    for (int g = 0; g < 41; ++g) {
        BODY(1, 0, 0);
        BODY(2, 1, 0);
        BODY(0, 2, 0);
    }
    BODY(1, 0, 0);   // t=124, stages ch126 -> buf0
    BODY(2, 1, 0);   // t=125, stages ch127 -> buf1
    BODY(0, 2, 1);   // t=126, reg f1(127) only
    BODY(1, 0, 2);   // t=127

#undef STAGE
#undef COMP
#undef BODY

    if (tid < 1008) {
        const float s = 1.0f / 128.0f;
        float* ob = out + (((size_t)(b * 81 + di * 9)) * H + h) * W + G * 4;
#pragma unroll
        for (int dj = 0; dj < 9; ++dj) {
            f32x4 ov = {acc[dj][0] * s, acc[dj][1] * s,
                        acc[dj][2] * s, acc[dj][3] * s};
            *(f32x4*)(ob + (size_t)dj * HW) = ov;
        }
    }
}

extern "C" void kernel_launch(void* const* d_in, const int* in_sizes, int n_in,
                              void* d_out, int out_size, void* d_ws, size_t ws_size,
                              hipStream_t stream) {
    const float* feat1 = (const float*)d_in[0];
    const float* feat2 = (const float*)d_in[1];
    float* out = (float*)d_out;
    // 256 zeroed bytes: broadcast-source for vertically-OOB feat2 rows.
    hipMemsetAsync(d_ws, 0, 256, stream);
    cv_kernel<<<dim3(1024), dim3(1024), 0, stream>>>(
        feat1, feat2, (const float*)d_ws, out);
}